// Round 10
// baseline (927.074 us; speedup 1.0000x reference)
//
#include <hip/hip_runtime.h>

// 3-layer sparse conv, gather formulation, zero atomics.
// R10: conv1 merged to full-64 channels per lane (R9's j-split x2 duplicated
// every t1 read and every random 32B x-gather; with LDS-staged stores the
// split no longer buys anything). Two-pass LDS epilogue keeps staging at
// [256][33] (33KB), full-sector cooperative stores per 32-ch half.

#define TPB 256

// m204 bijective XCD-chunk swizzle
__device__ __forceinline__ int xcd_chunk(int bid, int nwg) {
  int q = nwg >> 3, r = nwg & 7;
  int xcd = bid & 7, idx = bid >> 3;
  int base = (xcd < r) ? xcd * (q + 1) : r * (q + 1) + (xcd - r) * q;
  return base + idx;
}

__global__ void __launch_bounds__(TPB)
k_build(const int* __restrict__ mi, const int* __restrict__ mo,
        int* __restrict__ tbl, int L, int n_out) {
  int k = blockIdx.y;
  int p = blockIdx.x * TPB + threadIdx.x;
  if (p >= L) return;
  int out = mo[(size_t)k * L + p];
  bool valid = out < n_out;                 // pads point at dummy row n_out
  if (__ballot(valid) == 0ull) return;      // pads are a contiguous tail
  if (valid) tbl[(size_t)k * n_out + out] = mi[(size_t)k * L + p];
}

// conv1: 8 -> 64, 27 offsets. lane = output row, full 64 channels.
// Rolling 1-deep prefetch; two-pass LDS-staged coalesced output.
__global__ void __launch_bounds__(TPB)
k_conv1(const float* __restrict__ x, const float* __restrict__ W1,
        const float* __restrict__ b1, const int* __restrict__ t1,
        float* __restrict__ h1, int n1) {
  __shared__ float st[256][33];             // padded; reused across 2 passes
  int tid = threadIdx.x;
  int r0 = blockIdx.x * TPB;
  int r = r0 + tid;
  int rc = r < n1 ? r : n1 - 1;             // clamp; no early return (barriers)
  float acc[64];
#pragma unroll
  for (int j = 0; j < 64; ++j) acc[j] = 0.f;

  int icur = t1[rc];                                       // k=0 idx
  const float4* xp = (const float4*)(x + (size_t)(icur >= 0 ? icur : 0) * 8);
  float4 ca = xp[0], cb = xp[1];
  bool vcur = icur >= 0;
#pragma unroll 1
  for (int k = 0; k < 27; ++k) {
    // prefetch k+1 (unconditional loads; mask applied at use)
    int inext = (k < 26) ? t1[(size_t)(k + 1) * n1 + rc] : -1;
    const float4* np = (const float4*)(x + (size_t)(inext >= 0 ? inext : 0) * 8);
    float4 na = np[0], nb = np[1];
    if (!vcur) { ca = make_float4(0.f,0.f,0.f,0.f); cb = make_float4(0.f,0.f,0.f,0.f); }
    if (__ballot(vcur) != 0ull) {
      float xv[8] = {ca.x, ca.y, ca.z, ca.w, cb.x, cb.y, cb.z, cb.w};
      const float* __restrict__ Wk = W1 + (size_t)k * 512;        // wave-uniform
#pragma unroll
      for (int i = 0; i < 8; ++i)
#pragma unroll
        for (int j = 0; j < 64; ++j)
          acc[j] = fmaf(xv[i], Wk[i * 64 + j], acc[j]);
    }
    ca = na; cb = nb; vcur = inext >= 0;
  }
  // two-pass epilogue: stage 32 ch in LDS, cooperative full-sector stores.
#pragma unroll 1
  for (int half = 0; half < 2; ++half) {
    int j0 = half * 32;
    __syncthreads();                        // protect reuse of st
#pragma unroll
    for (int j = 0; j < 32; ++j)
      st[tid][j] = fmaxf(acc[j0 + j] + b1[j0 + j], 0.f);
    __syncthreads();
    // each instr's 64 lanes cover 8x128B contiguous chunks -> full sectors
#pragma unroll
    for (int i = 0; i < 8; ++i) {
      int f = i * 256 + tid;
      int row = f >> 3, q = f & 7;
      int g = r0 + row;
      if (g < n1) {
        float4 v = make_float4(st[row][4*q+0], st[row][4*q+1],
                               st[row][4*q+2], st[row][4*q+3]);
        *(float4*)(h1 + (size_t)g * 64 + j0 + 4 * q) = v;
      }
    }
  }
}

// conv2: 64 -> 64, 8 offsets. row-per-lane, j-quarter per block, XCD-chunk
// swizzled; idx prefetched one k ahead. (R8 structure, unchanged.)
__global__ void __launch_bounds__(TPB)
k_conv2(const float* __restrict__ h1, const float* __restrict__ W2,
        const float* __restrict__ b2, const int* __restrict__ t2,
        float* __restrict__ h2, int n1, int n2, int nwg) {
  int b = xcd_chunk(blockIdx.x, nwg);
  int jq = b & 3, xb = b >> 2;
  int r = xb * TPB + threadIdx.x;
  if (r >= n2) return;
  int j0 = jq * 16;
  float acc[16];
#pragma unroll
  for (int j = 0; j < 16; ++j) acc[j] = 0.f;
  int idx = t2[r];                          // k=0
#pragma unroll 1
  for (int k = 0; k < 8; ++k) {
    int inext = (k < 7) ? t2[(size_t)(k + 1) * n2 + r] : 0;
    int row = idx >= 0 ? idx : n1;          // zero row
    const float4* xr = (const float4*)(h1 + (size_t)row * 64);
    const float* __restrict__ Wk = W2 + (size_t)k * 4096 + j0;
#pragma unroll 4
    for (int c = 0; c < 16; ++c) {
      float4 xv = xr[c];
#pragma unroll
      for (int j = 0; j < 16; ++j) {
        acc[j] = fmaf(xv.x, Wk[(4*c+0)*64 + j], acc[j]);
        acc[j] = fmaf(xv.y, Wk[(4*c+1)*64 + j], acc[j]);
        acc[j] = fmaf(xv.z, Wk[(4*c+2)*64 + j], acc[j]);
        acc[j] = fmaf(xv.w, Wk[(4*c+3)*64 + j], acc[j]);
      }
    }
    idx = inext;
  }
  float4* yr = (float4*)(h2 + (size_t)r * 64 + j0);
#pragma unroll
  for (int q = 0; q < 4; ++q) {
    float4 o;
    o.x = fmaxf(acc[4*q+0] + b2[j0+4*q+0], 0.f);
    o.y = fmaxf(acc[4*q+1] + b2[j0+4*q+1], 0.f);
    o.z = fmaxf(acc[4*q+2] + b2[j0+4*q+2], 0.f);
    o.w = fmaxf(acc[4*q+3] + b2[j0+4*q+3], 0.f);
    yr[q] = o;
  }
}

// conv3: 64 -> 8, 27 offsets. 128-row blocks, 4 waves k-split (k ≡ w mod 4),
// 2 rows per lane (independent chains -> 2x MLP), SGPR W3, padded-LDS reduce.
__global__ void __launch_bounds__(TPB)
k_conv3(const float* __restrict__ h2, const float* __restrict__ W3,
        const float* __restrict__ b3, const int* __restrict__ t3,
        float* __restrict__ out, int n2, int nwg) {
  __shared__ float red[4][128][9];          // 18.4 KB
  int b = xcd_chunk(blockIdx.x, nwg);
  int w = __builtin_amdgcn_readfirstlane(threadIdx.x >> 6);
  int l = threadIdx.x & 63;
  int R = b * 128;
  int rA = R + l, rB = R + 64 + l;
  int rcA = rA < n2 ? rA : n2 - 1;
  int rcB = rB < n2 ? rB : n2 - 1;
  float accA[8], accB[8];
#pragma unroll
  for (int j = 0; j < 8; ++j) { accA[j] = 0.f; accB[j] = 0.f; }
  int nk = (w < 3) ? 7 : 6;                 // k = w + 4*i, k < 27
  int idxA = t3[(size_t)w * n2 + rcA];
  int idxB = t3[(size_t)w * n2 + rcB];
#pragma unroll 1
  for (int i = 0; i < nk; ++i) {
    int k = w + 4 * i;
    int rowA = idxA >= 0 ? idxA : n2;       // zero row
    int rowB = idxB >= 0 ? idxB : n2;
    if (i + 1 < nk) {
      idxA = t3[(size_t)(k + 4) * n2 + rcA];
      idxB = t3[(size_t)(k + 4) * n2 + rcB];
    }
    const float4* xrA = (const float4*)(h2 + (size_t)rowA * 64);
    const float4* xrB = (const float4*)(h2 + (size_t)rowB * 64);
    const float* __restrict__ Wk = W3 + (size_t)k * 512;   // SGPR (k uniform)
#pragma unroll
    for (int c = 0; c < 16; ++c) {
      float4 xv = xrA[c];
      float hv[4] = {xv.x, xv.y, xv.z, xv.w};
#pragma unroll
      for (int u = 0; u < 4; ++u)
#pragma unroll
        for (int j = 0; j < 8; ++j)
          accA[j] = fmaf(hv[u], Wk[(4*c+u)*8 + j], accA[j]);
    }
#pragma unroll
    for (int c = 0; c < 16; ++c) {
      float4 xv = xrB[c];
      float hv[4] = {xv.x, xv.y, xv.z, xv.w};
#pragma unroll
      for (int u = 0; u < 4; ++u)
#pragma unroll
        for (int j = 0; j < 8; ++j)
          accB[j] = fmaf(hv[u], Wk[(4*c+u)*8 + j], accB[j]);
    }
  }
#pragma unroll
  for (int j = 0; j < 8; ++j) {
    red[w][l][j] = accA[j];
    red[w][64 + l][j] = accB[j];
  }
  __syncthreads();
  // 1024 outputs (128 rows x 8 ch), coalesced
#pragma unroll
  for (int t = threadIdx.x; t < 1024; t += TPB) {
    int row = t >> 3, ch = t & 7;
    int g = R + row;
    if (g < n2) {
      float s = red[0][row][ch] + red[1][row][ch]
              + red[2][row][ch] + red[3][row][ch];
      out[(size_t)g * 8 + ch] = s + b3[ch];
    }
  }
}

extern "C" void kernel_launch(void* const* d_in, const int* in_sizes, int n_in,
                              void* d_out, int out_size, void* d_ws, size_t ws_size,
                              hipStream_t stream) {
  const float* feats = (const float*)d_in[0];
  const float* W1 = (const float*)d_in[1];
  const float* b1 = (const float*)d_in[2];
  const float* W2 = (const float*)d_in[3];
  const float* b2 = (const float*)d_in[4];
  const float* W3 = (const float*)d_in[5];
  const float* b3 = (const float*)d_in[6];
  const int* m1i = (const int*)d_in[7];
  const int* m1o = (const int*)d_in[8];
  const int* m2i = (const int*)d_in[9];
  const int* m2o = (const int*)d_in[10];
  const int* m3i = (const int*)d_in[11];
  const int* m3o = (const int*)d_in[12];

  int n1 = in_sizes[0] / 8;
  int L1 = in_sizes[7] / 27;
  int L2 = in_sizes[9] / 8;
  int L3 = in_sizes[11] / 27;
  int n2 = out_size / 8;

  // Workspace layout (t1 aliases the y2 region: t1 dead before conv2 writes y2)
  char* ws = (char*)d_ws;
  size_t y1_bytes = (size_t)(n1 + 1) * 64 * sizeof(float);
  size_t y2_bytes = (size_t)(n2 + 1) * 64 * sizeof(float);
  size_t t1_bytes = (size_t)27 * n1 * sizeof(int);
  size_t reg1_bytes = y2_bytes > t1_bytes ? y2_bytes : t1_bytes;
  float* y1 = (float*)ws;                              // h1: (n1+1) x 64
  float* y2 = (float*)(ws + y1_bytes);                 // h2: (n2+1) x 64
  int* t1 = (int*)(ws + y1_bytes);                     // alias (27 x n1)
  int* t2 = (int*)(ws + y1_bytes + reg1_bytes);        // 8 x n2
  int* t3 = (int*)(ws + y1_bytes + reg1_bytes + (size_t)8 * n2 * sizeof(int));

  hipMemsetAsync(t1, 0xFF, t1_bytes, stream);
  hipMemsetAsync(t2, 0xFF, (size_t)35 * n2 * sizeof(int), stream);  // t2+t3 contiguous

  k_build<<<dim3((L1 + TPB - 1) / TPB, 27), TPB, 0, stream>>>(m1i, m1o, t1, L1, n1);
  k_build<<<dim3((L2 + TPB - 1) / TPB, 8), TPB, 0, stream>>>(m2i, m2o, t2, L2, n2);
  k_build<<<dim3((L3 + TPB - 1) / TPB, 27), TPB, 0, stream>>>(m3i, m3o, t3, L3, n2);

  k_conv1<<<(n1 + TPB - 1) / TPB, TPB, 0, stream>>>(feats, W1, b1, t1, y1, n1);

  // zero rows for invalid gathers (y2's zero row lives inside the t1 alias
  // region, so write it only after conv1 has consumed t1)
  hipMemsetAsync(y1 + (size_t)n1 * 64, 0, 64 * sizeof(float), stream);
  hipMemsetAsync(y2 + (size_t)n2 * 64, 0, 64 * sizeof(float), stream);

  int nb2 = ((n2 + TPB - 1) / TPB) * 4;
  k_conv2<<<nb2, TPB, 0, stream>>>(y1, W2, b2, t2, y2, n1, n2, nb2);

  int nb3 = (n2 + 127) / 128;
  k_conv3<<<nb3, TPB, 0, stream>>>(y2, W3, b3, t3, (float*)d_out, n2, nb3);
}

// Round 11
// 560.569 us; speedup vs baseline: 1.6538x; 1.6538x over previous
//
#include <hip/hip_runtime.h>

// 3-layer sparse conv, gather formulation, zero atomics.
// R11: conv1 = acc[32] j-split x2 (R10's acc[64] spilled: compiler pins ~52
// VGPR and scratch-spilled the accumulators -> 1.9GB write traffic) + R9's
// LDS-staged full-sector stores, but staging 16ch/pass in [256][17] (17.4KB)
// so LDS caps 8-9 blocks/CU instead of R9's 4 (occ 36% -> ~full).

#define TPB 256

// m204 bijective XCD-chunk swizzle
__device__ __forceinline__ int xcd_chunk(int bid, int nwg) {
  int q = nwg >> 3, r = nwg & 7;
  int xcd = bid & 7, idx = bid >> 3;
  int base = (xcd < r) ? xcd * (q + 1) : r * (q + 1) + (xcd - r) * q;
  return base + idx;
}

__global__ void __launch_bounds__(TPB)
k_build(const int* __restrict__ mi, const int* __restrict__ mo,
        int* __restrict__ tbl, int L, int n_out) {
  int k = blockIdx.y;
  int p = blockIdx.x * TPB + threadIdx.x;
  if (p >= L) return;
  int out = mo[(size_t)k * L + p];
  bool valid = out < n_out;                 // pads point at dummy row n_out
  if (__ballot(valid) == 0ull) return;      // pads are a contiguous tail
  if (valid) tbl[(size_t)k * n_out + out] = mi[(size_t)k * L + p];
}

// conv1: 8 -> 64, 27 offsets. lane = output row, blockIdx.y = j-half (32 ch).
// Rolling 1-deep prefetch; 2x16ch LDS-staged full-sector stores.
__global__ void __launch_bounds__(TPB)
k_conv1(const float* __restrict__ x, const float* __restrict__ W1,
        const float* __restrict__ b1, const int* __restrict__ t1,
        float* __restrict__ h1, int n1) {
  __shared__ float st[256][17];             // 17.4KB; reused across 2 passes
  int tid = threadIdx.x;
  int r0 = blockIdx.x * TPB;
  int r = r0 + tid;
  int rc = r < n1 ? r : n1 - 1;             // clamp; no early return (barriers)
  int j0 = blockIdx.y * 32;
  float acc[32];
#pragma unroll
  for (int j = 0; j < 32; ++j) acc[j] = 0.f;

  int icur = t1[rc];                                       // k=0 idx
  const float4* xp = (const float4*)(x + (size_t)(icur >= 0 ? icur : 0) * 8);
  float4 ca = xp[0], cb = xp[1];
  bool vcur = icur >= 0;
#pragma unroll 1
  for (int k = 0; k < 27; ++k) {
    // prefetch k+1 (unconditional loads; mask applied at use)
    int inext = (k < 26) ? t1[(size_t)(k + 1) * n1 + rc] : -1;
    const float4* np = (const float4*)(x + (size_t)(inext >= 0 ? inext : 0) * 8);
    float4 na = np[0], nb = np[1];
    if (!vcur) { ca = make_float4(0.f,0.f,0.f,0.f); cb = make_float4(0.f,0.f,0.f,0.f); }
    if (__ballot(vcur) != 0ull) {
      float xv[8] = {ca.x, ca.y, ca.z, ca.w, cb.x, cb.y, cb.z, cb.w};
      const float* __restrict__ Wk = W1 + (size_t)k * 512 + j0;   // wave-uniform
#pragma unroll
      for (int i = 0; i < 8; ++i)
#pragma unroll
        for (int j = 0; j < 32; ++j)
          acc[j] = fmaf(xv[i], Wk[i * 64 + j], acc[j]);
    }
    ca = na; cb = nb; vcur = inext >= 0;
  }
  // epilogue: 2 passes x 16 channels; cooperative full-sector stores.
#pragma unroll 1
  for (int half = 0; half < 2; ++half) {
    int c0 = half * 16;
    __syncthreads();                        // protect st reuse
#pragma unroll
    for (int j = 0; j < 16; ++j)
      st[tid][j] = fmaxf(acc[c0 + j] + b1[j0 + c0 + j], 0.f);
    __syncthreads();
    // 1024 float4s; each instr: 64 lanes cover 16 rows x 64B full sectors
#pragma unroll
    for (int i = 0; i < 4; ++i) {
      int f = i * 256 + tid;
      int row = f >> 2, q = f & 3;
      int g = r0 + row;
      if (g < n1) {
        float4 v = make_float4(st[row][4*q+0], st[row][4*q+1],
                               st[row][4*q+2], st[row][4*q+3]);
        *(float4*)(h1 + (size_t)g * 64 + j0 + c0 + 4 * q) = v;
      }
    }
  }
}

// conv2: 64 -> 64, 8 offsets. row-per-lane, j-quarter per block, XCD-chunk
// swizzled; idx prefetched one k ahead. (R8 structure, unchanged.)
__global__ void __launch_bounds__(TPB)
k_conv2(const float* __restrict__ h1, const float* __restrict__ W2,
        const float* __restrict__ b2, const int* __restrict__ t2,
        float* __restrict__ h2, int n1, int n2, int nwg) {
  int b = xcd_chunk(blockIdx.x, nwg);
  int jq = b & 3, xb = b >> 2;
  int r = xb * TPB + threadIdx.x;
  if (r >= n2) return;
  int j0 = jq * 16;
  float acc[16];
#pragma unroll
  for (int j = 0; j < 16; ++j) acc[j] = 0.f;
  int idx = t2[r];                          // k=0
#pragma unroll 1
  for (int k = 0; k < 8; ++k) {
    int inext = (k < 7) ? t2[(size_t)(k + 1) * n2 + r] : 0;
    int row = idx >= 0 ? idx : n1;          // zero row
    const float4* xr = (const float4*)(h1 + (size_t)row * 64);
    const float* __restrict__ Wk = W2 + (size_t)k * 4096 + j0;
#pragma unroll 4
    for (int c = 0; c < 16; ++c) {
      float4 xv = xr[c];
#pragma unroll
      for (int j = 0; j < 16; ++j) {
        acc[j] = fmaf(xv.x, Wk[(4*c+0)*64 + j], acc[j]);
        acc[j] = fmaf(xv.y, Wk[(4*c+1)*64 + j], acc[j]);
        acc[j] = fmaf(xv.z, Wk[(4*c+2)*64 + j], acc[j]);
        acc[j] = fmaf(xv.w, Wk[(4*c+3)*64 + j], acc[j]);
      }
    }
    idx = inext;
  }
  float4* yr = (float4*)(h2 + (size_t)r * 64 + j0);
#pragma unroll
  for (int q = 0; q < 4; ++q) {
    float4 o;
    o.x = fmaxf(acc[4*q+0] + b2[j0+4*q+0], 0.f);
    o.y = fmaxf(acc[4*q+1] + b2[j0+4*q+1], 0.f);
    o.z = fmaxf(acc[4*q+2] + b2[j0+4*q+2], 0.f);
    o.w = fmaxf(acc[4*q+3] + b2[j0+4*q+3], 0.f);
    yr[q] = o;
  }
}

// conv3: 64 -> 8, 27 offsets. 128-row blocks, 4 waves k-split (k ≡ w mod 4),
// 2 rows per lane (independent chains -> 2x MLP), SGPR W3, padded-LDS reduce.
__global__ void __launch_bounds__(TPB)
k_conv3(const float* __restrict__ h2, const float* __restrict__ W3,
        const float* __restrict__ b3, const int* __restrict__ t3,
        float* __restrict__ out, int n2, int nwg) {
  __shared__ float red[4][128][9];          // 18.4 KB
  int b = xcd_chunk(blockIdx.x, nwg);
  int w = __builtin_amdgcn_readfirstlane(threadIdx.x >> 6);
  int l = threadIdx.x & 63;
  int R = b * 128;
  int rA = R + l, rB = R + 64 + l;
  int rcA = rA < n2 ? rA : n2 - 1;
  int rcB = rB < n2 ? rB : n2 - 1;
  float accA[8], accB[8];
#pragma unroll
  for (int j = 0; j < 8; ++j) { accA[j] = 0.f; accB[j] = 0.f; }
  int nk = (w < 3) ? 7 : 6;                 // k = w + 4*i, k < 27
  int idxA = t3[(size_t)w * n2 + rcA];
  int idxB = t3[(size_t)w * n2 + rcB];
#pragma unroll 1
  for (int i = 0; i < nk; ++i) {
    int k = w + 4 * i;
    int rowA = idxA >= 0 ? idxA : n2;       // zero row
    int rowB = idxB >= 0 ? idxB : n2;
    if (i + 1 < nk) {
      idxA = t3[(size_t)(k + 4) * n2 + rcA];
      idxB = t3[(size_t)(k + 4) * n2 + rcB];
    }
    const float4* xrA = (const float4*)(h2 + (size_t)rowA * 64);
    const float4* xrB = (const float4*)(h2 + (size_t)rowB * 64);
    const float* __restrict__ Wk = W3 + (size_t)k * 512;   // SGPR (k uniform)
#pragma unroll
    for (int c = 0; c < 16; ++c) {
      float4 xv = xrA[c];
      float hv[4] = {xv.x, xv.y, xv.z, xv.w};
#pragma unroll
      for (int u = 0; u < 4; ++u)
#pragma unroll
        for (int j = 0; j < 8; ++j)
          accA[j] = fmaf(hv[u], Wk[(4*c+u)*8 + j], accA[j]);
    }
#pragma unroll
    for (int c = 0; c < 16; ++c) {
      float4 xv = xrB[c];
      float hv[4] = {xv.x, xv.y, xv.z, xv.w};
#pragma unroll
      for (int u = 0; u < 4; ++u)
#pragma unroll
        for (int j = 0; j < 8; ++j)
          accB[j] = fmaf(hv[u], Wk[(4*c+u)*8 + j], accB[j]);
    }
  }
#pragma unroll
  for (int j = 0; j < 8; ++j) {
    red[w][l][j] = accA[j];
    red[w][64 + l][j] = accB[j];
  }
  __syncthreads();
  // 1024 outputs (128 rows x 8 ch), coalesced
#pragma unroll
  for (int t = threadIdx.x; t < 1024; t += TPB) {
    int row = t >> 3, ch = t & 7;
    int g = R + row;
    if (g < n2) {
      float s = red[0][row][ch] + red[1][row][ch]
              + red[2][row][ch] + red[3][row][ch];
      out[(size_t)g * 8 + ch] = s + b3[ch];
    }
  }
}

extern "C" void kernel_launch(void* const* d_in, const int* in_sizes, int n_in,
                              void* d_out, int out_size, void* d_ws, size_t ws_size,
                              hipStream_t stream) {
  const float* feats = (const float*)d_in[0];
  const float* W1 = (const float*)d_in[1];
  const float* b1 = (const float*)d_in[2];
  const float* W2 = (const float*)d_in[3];
  const float* b2 = (const float*)d_in[4];
  const float* W3 = (const float*)d_in[5];
  const float* b3 = (const float*)d_in[6];
  const int* m1i = (const int*)d_in[7];
  const int* m1o = (const int*)d_in[8];
  const int* m2i = (const int*)d_in[9];
  const int* m2o = (const int*)d_in[10];
  const int* m3i = (const int*)d_in[11];
  const int* m3o = (const int*)d_in[12];

  int n1 = in_sizes[0] / 8;
  int L1 = in_sizes[7] / 27;
  int L2 = in_sizes[9] / 8;
  int L3 = in_sizes[11] / 27;
  int n2 = out_size / 8;

  // Workspace layout (t1 aliases the y2 region: t1 dead before conv2 writes y2)
  char* ws = (char*)d_ws;
  size_t y1_bytes = (size_t)(n1 + 1) * 64 * sizeof(float);
  size_t y2_bytes = (size_t)(n2 + 1) * 64 * sizeof(float);
  size_t t1_bytes = (size_t)27 * n1 * sizeof(int);
  size_t reg1_bytes = y2_bytes > t1_bytes ? y2_bytes : t1_bytes;
  float* y1 = (float*)ws;                              // h1: (n1+1) x 64
  float* y2 = (float*)(ws + y1_bytes);                 // h2: (n2+1) x 64
  int* t1 = (int*)(ws + y1_bytes);                     // alias (27 x n1)
  int* t2 = (int*)(ws + y1_bytes + reg1_bytes);        // 8 x n2
  int* t3 = (int*)(ws + y1_bytes + reg1_bytes + (size_t)8 * n2 * sizeof(int));

  hipMemsetAsync(t1, 0xFF, t1_bytes, stream);
  hipMemsetAsync(t2, 0xFF, (size_t)35 * n2 * sizeof(int), stream);  // t2+t3 contiguous

  k_build<<<dim3((L1 + TPB - 1) / TPB, 27), TPB, 0, stream>>>(m1i, m1o, t1, L1, n1);
  k_build<<<dim3((L2 + TPB - 1) / TPB, 8), TPB, 0, stream>>>(m2i, m2o, t2, L2, n2);
  k_build<<<dim3((L3 + TPB - 1) / TPB, 27), TPB, 0, stream>>>(m3i, m3o, t3, L3, n2);

  k_conv1<<<dim3((n1 + TPB - 1) / TPB, 2), TPB, 0, stream>>>(feats, W1, b1, t1, y1, n1);

  // zero rows for invalid gathers (y2's zero row lives inside the t1 alias
  // region, so write it only after conv1 has consumed t1)
  hipMemsetAsync(y1 + (size_t)n1 * 64, 0, 64 * sizeof(float), stream);
  hipMemsetAsync(y2 + (size_t)n2 * 64, 0, 64 * sizeof(float), stream);

  int nb2 = ((n2 + TPB - 1) / TPB) * 4;
  k_conv2<<<nb2, TPB, 0, stream>>>(y1, W2, b2, t2, y2, n1, n2, nb2);

  int nb3 = (n2 + 127) / 128;
  k_conv3<<<nb3, TPB, 0, stream>>>(y2, W3, b3, t3, (float*)d_out, n2, nb3);
}

// Round 14
// 549.830 us; speedup vs baseline: 1.6861x; 1.0195x over previous
//
#include <hip/hip_runtime.h>

// 3-layer sparse conv, gather formulation, zero atomics.
// R12 (2nd resubmit after broker timeouts): conv3 = 512-thread / 8-wave
// blocks, 64 rows, k ≡ w (mod 8). R11 showed 2-rows/lane (ILP) REGRESSED vs
// 1-row/lane (occ 54->42), and nothing hw-side caps occupancy -> go pure TLP:
// halve per-wave k work, double resident waves (LDS 18.4KB -> 4 blk/CU =
// 32 waves = 100% potential). SGPR W3 + in-block k-locality preserved.

#define TPB 256
#define TPB3 512

// m204 bijective XCD-chunk swizzle
__device__ __forceinline__ int xcd_chunk(int bid, int nwg) {
  int q = nwg >> 3, r = nwg & 7;
  int xcd = bid & 7, idx = bid >> 3;
  int base = (xcd < r) ? xcd * (q + 1) : r * (q + 1) + (xcd - r) * q;
  return base + idx;
}

__global__ void __launch_bounds__(TPB)
k_build(const int* __restrict__ mi, const int* __restrict__ mo,
        int* __restrict__ tbl, int L, int n_out) {
  int k = blockIdx.y;
  int p = blockIdx.x * TPB + threadIdx.x;
  if (p >= L) return;
  int out = mo[(size_t)k * L + p];
  bool valid = out < n_out;                 // pads point at dummy row n_out
  if (__ballot(valid) == 0ull) return;      // pads are a contiguous tail
  if (valid) tbl[(size_t)k * n_out + out] = mi[(size_t)k * L + p];
}

// conv1: 8 -> 64, 27 offsets. lane = output row, blockIdx.y = j-half (32 ch).
// Rolling 1-deep prefetch; 2x16ch LDS-staged full-sector stores. (R11 form.)
__global__ void __launch_bounds__(TPB)
k_conv1(const float* __restrict__ x, const float* __restrict__ W1,
        const float* __restrict__ b1, const int* __restrict__ t1,
        float* __restrict__ h1, int n1) {
  __shared__ float st[256][17];             // 17.4KB; reused across 2 passes
  int tid = threadIdx.x;
  int r0 = blockIdx.x * TPB;
  int r = r0 + tid;
  int rc = r < n1 ? r : n1 - 1;             // clamp; no early return (barriers)
  int j0 = blockIdx.y * 32;
  float acc[32];
#pragma unroll
  for (int j = 0; j < 32; ++j) acc[j] = 0.f;

  int icur = t1[rc];                                       // k=0 idx
  const float4* xp = (const float4*)(x + (size_t)(icur >= 0 ? icur : 0) * 8);
  float4 ca = xp[0], cb = xp[1];
  bool vcur = icur >= 0;
#pragma unroll 1
  for (int k = 0; k < 27; ++k) {
    // prefetch k+1 (unconditional loads; mask applied at use)
    int inext = (k < 26) ? t1[(size_t)(k + 1) * n1 + rc] : -1;
    const float4* np = (const float4*)(x + (size_t)(inext >= 0 ? inext : 0) * 8);
    float4 na = np[0], nb = np[1];
    if (!vcur) { ca = make_float4(0.f,0.f,0.f,0.f); cb = make_float4(0.f,0.f,0.f,0.f); }
    if (__ballot(vcur) != 0ull) {
      float xv[8] = {ca.x, ca.y, ca.z, ca.w, cb.x, cb.y, cb.z, cb.w};
      const float* __restrict__ Wk = W1 + (size_t)k * 512 + j0;   // wave-uniform
#pragma unroll
      for (int i = 0; i < 8; ++i)
#pragma unroll
        for (int j = 0; j < 32; ++j)
          acc[j] = fmaf(xv[i], Wk[i * 64 + j], acc[j]);
    }
    ca = na; cb = nb; vcur = inext >= 0;
  }
  // epilogue: 2 passes x 16 channels; cooperative full-sector stores.
#pragma unroll 1
  for (int half = 0; half < 2; ++half) {
    int c0 = half * 16;
    __syncthreads();                        // protect st reuse
#pragma unroll
    for (int j = 0; j < 16; ++j)
      st[tid][j] = fmaxf(acc[c0 + j] + b1[j0 + c0 + j], 0.f);
    __syncthreads();
    // 1024 float4s; each instr: 64 lanes cover 16 rows x 64B full sectors
#pragma unroll
    for (int i = 0; i < 4; ++i) {
      int f = i * 256 + tid;
      int row = f >> 2, q = f & 3;
      int g = r0 + row;
      if (g < n1) {
        float4 v = make_float4(st[row][4*q+0], st[row][4*q+1],
                               st[row][4*q+2], st[row][4*q+3]);
        *(float4*)(h1 + (size_t)g * 64 + j0 + c0 + 4 * q) = v;
      }
    }
  }
}

// conv2: 64 -> 64, 8 offsets. row-per-lane, j-quarter per block, XCD-chunk
// swizzled; idx prefetched one k ahead. (R8 structure, unchanged.)
__global__ void __launch_bounds__(TPB)
k_conv2(const float* __restrict__ h1, const float* __restrict__ W2,
        const float* __restrict__ b2, const int* __restrict__ t2,
        float* __restrict__ h2, int n1, int n2, int nwg) {
  int b = xcd_chunk(blockIdx.x, nwg);
  int jq = b & 3, xb = b >> 2;
  int r = xb * TPB + threadIdx.x;
  if (r >= n2) return;
  int j0 = jq * 16;
  float acc[16];
#pragma unroll
  for (int j = 0; j < 16; ++j) acc[j] = 0.f;
  int idx = t2[r];                          // k=0
#pragma unroll 1
  for (int k = 0; k < 8; ++k) {
    int inext = (k < 7) ? t2[(size_t)(k + 1) * n2 + r] : 0;
    int row = idx >= 0 ? idx : n1;          // zero row
    const float4* xr = (const float4*)(h1 + (size_t)row * 64);
    const float* __restrict__ Wk = W2 + (size_t)k * 4096 + j0;
#pragma unroll 4
    for (int c = 0; c < 16; ++c) {
      float4 xv = xr[c];
#pragma unroll
      for (int j = 0; j < 16; ++j) {
        acc[j] = fmaf(xv.x, Wk[(4*c+0)*64 + j], acc[j]);
        acc[j] = fmaf(xv.y, Wk[(4*c+1)*64 + j], acc[j]);
        acc[j] = fmaf(xv.z, Wk[(4*c+2)*64 + j], acc[j]);
        acc[j] = fmaf(xv.w, Wk[(4*c+3)*64 + j], acc[j]);
      }
    }
    idx = inext;
  }
  float4* yr = (float4*)(h2 + (size_t)r * 64 + j0);
#pragma unroll
  for (int q = 0; q < 4; ++q) {
    float4 o;
    o.x = fmaxf(acc[4*q+0] + b2[j0+4*q+0], 0.f);
    o.y = fmaxf(acc[4*q+1] + b2[j0+4*q+1], 0.f);
    o.z = fmaxf(acc[4*q+2] + b2[j0+4*q+2], 0.f);
    o.w = fmaxf(acc[4*q+3] + b2[j0+4*q+3], 0.f);
    yr[q] = o;
  }
}

// conv3: 64 -> 8, 27 offsets. 64-row blocks, 8 waves (512 thr), 1 row/lane,
// wave w handles k ∈ {w, w+8, w+16, w+24}. SGPR W3, padded-LDS reduce.
__global__ void __launch_bounds__(TPB3)
k_conv3(const float* __restrict__ h2, const float* __restrict__ W3,
        const float* __restrict__ b3, const int* __restrict__ t3,
        float* __restrict__ out, int n2, int nwg) {
  __shared__ float red[8][64][9];           // 18.4 KB
  int b = xcd_chunk(blockIdx.x, nwg);
  int w = __builtin_amdgcn_readfirstlane(threadIdx.x >> 6);  // 0..7
  int l = threadIdx.x & 63;
  int R = b * 64;
  int r = R + l;
  int rc = r < n2 ? r : n2 - 1;             // clamp; store guarded
  float acc[8];
#pragma unroll
  for (int j = 0; j < 8; ++j) acc[j] = 0.f;
  int nk = (w < 3) ? 4 : 3;                 // k = w + 8*i < 27
  int idx = t3[(size_t)w * n2 + rc];        // prefetch i=0
#pragma unroll 1
  for (int i = 0; i < nk; ++i) {
    int k = w + 8 * i;
    int row = idx >= 0 ? idx : n2;          // zero row
    if (i + 1 < nk) idx = t3[(size_t)(k + 8) * n2 + rc];
    const float4* xr = (const float4*)(h2 + (size_t)row * 64);
    const float* __restrict__ Wk = W3 + (size_t)k * 512;   // SGPR (k uniform)
#pragma unroll
    for (int c = 0; c < 16; ++c) {
      float4 xv = xr[c];
      float hv[4] = {xv.x, xv.y, xv.z, xv.w};
#pragma unroll
      for (int u = 0; u < 4; ++u)
#pragma unroll
        for (int j = 0; j < 8; ++j)
          acc[j] = fmaf(hv[u], Wk[(4*c+u)*8 + j], acc[j]);
    }
  }
#pragma unroll
  for (int j = 0; j < 8; ++j) red[w][l][j] = acc[j];
  __syncthreads();
  // 512 outputs (64 rows x 8 ch); one per thread, coalesced.
  {
    int t = threadIdx.x;
    int row = t >> 3, ch = t & 7;
    int g = R + row;
    if (g < n2) {
      float s = red[0][row][ch] + red[1][row][ch]
              + red[2][row][ch] + red[3][row][ch]
              + red[4][row][ch] + red[5][row][ch]
              + red[6][row][ch] + red[7][row][ch];
      out[(size_t)g * 8 + ch] = s + b3[ch];
    }
  }
}

extern "C" void kernel_launch(void* const* d_in, const int* in_sizes, int n_in,
                              void* d_out, int out_size, void* d_ws, size_t ws_size,
                              hipStream_t stream) {
  const float* feats = (const float*)d_in[0];
  const float* W1 = (const float*)d_in[1];
  const float* b1 = (const float*)d_in[2];
  const float* W2 = (const float*)d_in[3];
  const float* b2 = (const float*)d_in[4];
  const float* W3 = (const float*)d_in[5];
  const float* b3 = (const float*)d_in[6];
  const int* m1i = (const int*)d_in[7];
  const int* m1o = (const int*)d_in[8];
  const int* m2i = (const int*)d_in[9];
  const int* m2o = (const int*)d_in[10];
  const int* m3i = (const int*)d_in[11];
  const int* m3o = (const int*)d_in[12];

  int n1 = in_sizes[0] / 8;
  int L1 = in_sizes[7] / 27;
  int L2 = in_sizes[9] / 8;
  int L3 = in_sizes[11] / 27;
  int n2 = out_size / 8;

  // Workspace layout (t1 aliases the y2 region: t1 dead before conv2 writes y2)
  char* ws = (char*)d_ws;
  size_t y1_bytes = (size_t)(n1 + 1) * 64 * sizeof(float);
  size_t y2_bytes = (size_t)(n2 + 1) * 64 * sizeof(float);
  size_t t1_bytes = (size_t)27 * n1 * sizeof(int);
  size_t reg1_bytes = y2_bytes > t1_bytes ? y2_bytes : t1_bytes;
  float* y1 = (float*)ws;                              // h1: (n1+1) x 64
  float* y2 = (float*)(ws + y1_bytes);                 // h2: (n2+1) x 64
  int* t1 = (int*)(ws + y1_bytes);                     // alias (27 x n1)
  int* t2 = (int*)(ws + y1_bytes + reg1_bytes);        // 8 x n2
  int* t3 = (int*)(ws + y1_bytes + reg1_bytes + (size_t)8 * n2 * sizeof(int));

  hipMemsetAsync(t1, 0xFF, t1_bytes, stream);
  hipMemsetAsync(t2, 0xFF, (size_t)35 * n2 * sizeof(int), stream);  // t2+t3 contiguous

  k_build<<<dim3((L1 + TPB - 1) / TPB, 27), TPB, 0, stream>>>(m1i, m1o, t1, L1, n1);
  k_build<<<dim3((L2 + TPB - 1) / TPB, 8), TPB, 0, stream>>>(m2i, m2o, t2, L2, n2);
  k_build<<<dim3((L3 + TPB - 1) / TPB, 27), TPB, 0, stream>>>(m3i, m3o, t3, L3, n2);

  k_conv1<<<dim3((n1 + TPB - 1) / TPB, 2), TPB, 0, stream>>>(feats, W1, b1, t1, y1, n1);

  // zero rows for invalid gathers (y2's zero row lives inside the t1 alias
  // region, so write it only after conv1 has consumed t1)
  hipMemsetAsync(y1 + (size_t)n1 * 64, 0, 64 * sizeof(float), stream);
  hipMemsetAsync(y2 + (size_t)n2 * 64, 0, 64 * sizeof(float), stream);

  int nb2 = ((n2 + TPB - 1) / TPB) * 4;
  k_conv2<<<nb2, TPB, 0, stream>>>(y1, W2, b2, t2, y2, n1, n2, nb2);

  int nb3 = (n2 + 63) / 64;
  k_conv3<<<nb3, TPB3, 0, stream>>>(y2, W3, b3, t3, (float*)d_out, n2, nb3);
}